// Round 3
// baseline (198.942 us; speedup 1.0000x reference)
//
#include <hip/hip_runtime.h>
#include <math.h>

// Problem constants (match reference)
constexpr int   B_    = 2048;
constexpr int   L_    = 8192;
constexpr int   G_    = 256;
constexpr float BETA_ = 0.01f;
constexpr int   ITERS = L_ / (4 * 256);   // 8

// log(sigmoid(-x)) = -softplus(x) = -(max(x,0) + log(1 + exp(-|x|)))
// Hardware transcendentals (v_exp_f32/v_log_f32); rel err ~1e-5 << 5e-3 threshold.
__device__ __forceinline__ float log_sigmoid_neg(float x) {
    return -(fmaxf(x, 0.0f) + __logf(1.0f + __expf(-fabsf(x))));
}

// launch_bounds(256, 4): 4 waves/EU -> VGPR cap 128. We need ~110 to hold all
// 24 prefetched 16B loads in flight (the whole point: R2 showed VGPR=16 ->
// 1 outstanding load/wave -> latency-bound at 96us with every pipe idle).
extern "C" __global__ __launch_bounds__(256, 4)
void meta_loss_kernel(const float* __restrict__ logits,
                      const int*   __restrict__ true_y,
                      const int*   __restrict__ group_ids,
                      float*       __restrict__ out)
{
    __shared__ float s_gl[G_];    // per-group sum of log(1 - sigmoid(logit))
    __shared__ int   s_any[G_];   // per-group "any true label" flag
    __shared__ float s_part[4];   // per-wave partial sums

    const int t = threadIdx.x;
    const int b = blockIdx.x;

    s_gl[t]  = 0.0f;
    s_any[t] = 0;

    const float4* lg = (const float4*)(logits + (size_t)b * L_);
    const int4*   ty = (const int4*)(true_y + (size_t)b * L_);
    const int4*   gi = (const int4*)group_ids;

    // ---- Phase 1: issue ALL loads before consuming ANY (max MLP) ----
    float4 xs[ITERS];
    int4   ys[ITERS];
    int4   gs[ITERS];
    #pragma unroll
    for (int i = 0; i < ITERS; ++i) {
        const int idx = i * 256 + t;
        xs[i] = lg[idx];
        ys[i] = ty[idx];
        gs[i] = gi[idx];
    }

    __syncthreads();   // s_gl/s_any init visible (overlaps with loads in flight)

    // ---- Phase 2: transcendentals + LDS accumulation ----
    #pragma unroll
    for (int i = 0; i < ITERS; ++i) {
        const float4 x = xs[i];
        const int4   y = ys[i];
        const int4   g = gs[i];

        atomicAdd(&s_gl[g.x], log_sigmoid_neg(x.x));
        atomicAdd(&s_gl[g.y], log_sigmoid_neg(x.y));
        atomicAdd(&s_gl[g.z], log_sigmoid_neg(x.z));
        atomicAdd(&s_gl[g.w], log_sigmoid_neg(x.w));

        // racy identical-value store is safe (everyone writes 1)
        if (y.x) s_any[g.x] = 1;
        if (y.y) s_any[g.y] = 1;
        if (y.z) s_any[g.z] = 1;
        if (y.w) s_any[g.w] = 1;
    }
    __syncthreads();

    // Thread t owns group t (G_ == blockDim.x == 256)
    const float gl = s_gl[t];
    float term;
    if (s_any[t]) {
        term = fmaxf(gl, -100.0f);                    // meta_y = 1: log(p)
    } else {
        // log1p(-exp(gl)); gl==0 (empty group) -> -inf -> clamp. One call/thread.
        term = fmaxf(log1pf(-__expf(gl)), -100.0f);   // meta_y = 0: log(1-p)
    }

    // wave64 down-reduce, then cross-wave via LDS
    #pragma unroll
    for (int off = 32; off > 0; off >>= 1)
        term += __shfl_down(term, off, 64);
    if ((t & 63) == 0) s_part[t >> 6] = term;
    __syncthreads();

    if (t == 0) {
        const float s = s_part[0] + s_part[1] + s_part[2] + s_part[3];
        // bce = -mean(...)  -> contribution scaled by -BETA / (B*G)
        atomicAdd(out, s * (-BETA_ / ((float)B_ * (float)G_)));
    }
}

extern "C" void kernel_launch(void* const* d_in, const int* in_sizes, int n_in,
                              void* d_out, int out_size, void* d_ws, size_t ws_size,
                              hipStream_t stream) {
    const float* logits    = (const float*)d_in[0];
    const int*   true_y    = (const int*)d_in[1];
    const int*   group_ids = (const int*)d_in[2];
    float*       out       = (float*)d_out;

    // d_out is poisoned 0xAA before every launch; zero it (async memset is capture-safe)
    hipMemsetAsync(out, 0, sizeof(float), stream);

    meta_loss_kernel<<<B_, 256, 0, stream>>>(logits, true_y, group_ids, out);
}

// Round 4
// 166.333 us; speedup vs baseline: 1.1960x; 1.1960x over previous
//
#include <hip/hip_runtime.h>
#include <math.h>

// Problem constants (match reference)
constexpr int   B_    = 2048;
constexpr int   L_    = 8192;
constexpr int   G_    = 256;
constexpr float BETA_ = 0.01f;
constexpr float BIG_  = 1024.0f;   // y-flag encoding; |sum r| < 512 guaranteed (max ~330)

// log(sigmoid(-x)) = -softplus(x) = -(max(x,0) + log(1 + exp(-|x|)))
// HW transcendentals; rel err ~1e-5 << 5e-3 threshold (validated R2: absmax 0.0).
__device__ __forceinline__ float log_sigmoid_neg(float x) {
    return -(fmaxf(x, 0.0f) + __logf(1.0f + __expf(-fabsf(x))));
}

// ---------------------------------------------------------------------------
// k0: counting sort of labels by group (group_ids is row-invariant).
// Writes: g_offs[257] (exclusive starts), g_perm[8192] (u16 label indices,
// grouped). One block, 1024 threads. Runs once per launch; cost amortized
// over 2048 rows in the main kernel.
// ---------------------------------------------------------------------------
extern "C" __global__ __launch_bounds__(1024)
void build_perm_kernel(const int* __restrict__ group_ids,
                       int* __restrict__ g_offs,
                       unsigned short* __restrict__ g_perm)
{
    __shared__ int s_hist[G_];
    __shared__ int s_scan[G_];
    __shared__ int s_cur[G_];
    __shared__ unsigned short s_perm[L_];   // 16 KB

    const int t = threadIdx.x;              // 0..1023

    if (t < G_) s_hist[t] = 0;

    // coalesced: element l = i*1024 + t
    int ids[8];
    #pragma unroll
    for (int i = 0; i < 8; ++i) ids[i] = group_ids[i * 1024 + t];

    __syncthreads();

    #pragma unroll
    for (int i = 0; i < 8; ++i) atomicAdd(&s_hist[ids[i]], 1);
    __syncthreads();

    // Hillis-Steele inclusive scan over 256 counts (threads 0..255 active,
    // all threads hit the barriers)
    if (t < G_) s_scan[t] = s_hist[t];
    __syncthreads();
    for (int off = 1; off < G_; off <<= 1) {
        int v = 0;
        if (t < G_ && t >= off) v = s_scan[t - off];
        __syncthreads();
        if (t < G_) s_scan[t] += v;
        __syncthreads();
    }

    if (t < G_) {
        const int excl = s_scan[t] - s_hist[t];
        s_cur[t]  = excl;
        g_offs[t] = excl;
    }
    if (t == 0) g_offs[G_] = L_;
    __syncthreads();

    // scatter into LDS perm (random u16 LDS writes via cursor atomics)
    #pragma unroll
    for (int i = 0; i < 8; ++i) {
        const int l   = i * 1024 + t;
        const int pos = atomicAdd(&s_cur[ids[i]], 1);
        s_perm[pos] = (unsigned short)l;
    }
    __syncthreads();

    // coalesced 16 KB write-out
    ((int4*)g_perm)[t] = ((int4*)s_perm)[t];
}

// ---------------------------------------------------------------------------
// Main kernel: one block per row. ZERO atomics in the hot path (R3 showed the
// 8192 per-row ds_atomic_add_f32 were the ~100us floor: ~117 cyc/wave-op on
// the DS pipe while VALU=11%, HBM=8%).
// Phase 1: coalesced load, softplus, encode y-flag as +1024, store row to LDS.
// Phase 2: thread t gathers its group's elements (plain ds_read) and decodes.
// ---------------------------------------------------------------------------
extern "C" __global__ __launch_bounds__(256)
void meta_loss_kernel(const float* __restrict__ logits,
                      const int*   __restrict__ true_y,
                      const int*   __restrict__ g_offs,
                      const unsigned short* __restrict__ g_perm,
                      float*       __restrict__ out)
{
    __shared__ float s_row[L_];              // 32 KB: encoded per-label values
    __shared__ unsigned short s_perm[L_];    // 16 KB: staged permutation
    __shared__ float s_part[4];

    const int t = threadIdx.x;
    const int b = blockIdx.x;

    const float4* lg = (const float4*)(logits + (size_t)b * L_);
    const int4*   ty = (const int4*)(true_y + (size_t)b * L_);
    const int4*   pp = (const int4*)g_perm;
    float4* s_row4  = (float4*)s_row;
    int4*   s_perm4 = (int4*)s_perm;

    // my group's extent (L2-resident after first blocks)
    const int o0 = g_offs[t];
    const int o1 = g_offs[t + 1];

    // ---- Phase 1: stream row -> encoded LDS (coalesced, no atomics) ----
    #pragma unroll
    for (int i = 0; i < L_ / (4 * 256); ++i) {          // 8 iters
        const int idx = i * 256 + t;
        const float4 x = lg[idx];
        const int4   y = ty[idx];
        float4 r;
        r.x = log_sigmoid_neg(x.x) + (y.x ? BIG_ : 0.0f);
        r.y = log_sigmoid_neg(x.y) + (y.y ? BIG_ : 0.0f);
        r.z = log_sigmoid_neg(x.z) + (y.z ? BIG_ : 0.0f);
        r.w = log_sigmoid_neg(x.w) + (y.w ? BIG_ : 0.0f);
        s_row4[idx] = r;
    }
    // stage perm: 1024 int4 = 16 KB
    #pragma unroll
    for (int i = 0; i < 4; ++i) {
        const int idx = i * 256 + t;
        s_perm4[idx] = pp[idx];
    }
    __syncthreads();

    // ---- Phase 2: thread t owns group t; gather + decode ----
    float enc = 0.0f;
    for (int j = o0; j < o1; ++j) {
        enc += s_row[s_perm[j]];
    }
    const int   k  = __float2int_rn(enc * (1.0f / BIG_));  // count of true labels
    const float gl = enc - BIG_ * (float)k;                // sum log(1 - sigmoid)

    float term;
    if (k != 0) {
        term = fmaxf(gl, -100.0f);                    // meta_y = 1: log(p)
    } else {
        // gl == 0 (empty group) -> log1p(-1) = -inf -> clamped to -100
        term = fmaxf(log1pf(-__expf(gl)), -100.0f);   // meta_y = 0: log(1-p)
    }

    // block reduction
    #pragma unroll
    for (int off = 32; off > 0; off >>= 1)
        term += __shfl_down(term, off, 64);
    if ((t & 63) == 0) s_part[t >> 6] = term;
    __syncthreads();

    if (t == 0) {
        const float s = s_part[0] + s_part[1] + s_part[2] + s_part[3];
        atomicAdd(out, s * (-BETA_ / ((float)B_ * (float)G_)));
    }
}

extern "C" void kernel_launch(void* const* d_in, const int* in_sizes, int n_in,
                              void* d_out, int out_size, void* d_ws, size_t ws_size,
                              hipStream_t stream) {
    const float* logits    = (const float*)d_in[0];
    const int*   true_y    = (const int*)d_in[1];
    const int*   group_ids = (const int*)d_in[2];
    float*       out       = (float*)d_out;

    // workspace layout: [0,2048) offs ints (257 used), [2048, 2048+16384) perm u16
    int*            g_offs = (int*)d_ws;
    unsigned short* g_perm = (unsigned short*)((char*)d_ws + 2048);

    hipMemsetAsync(out, 0, sizeof(float), stream);

    build_perm_kernel<<<1, 1024, 0, stream>>>(group_ids, g_offs, g_perm);
    meta_loss_kernel<<<B_, 256, 0, stream>>>(logits, true_y, g_offs, g_perm, out);
}

// Round 5
// 161.876 us; speedup vs baseline: 1.2290x; 1.0275x over previous
//
#include <hip/hip_runtime.h>
#include <math.h>

// Problem constants (match reference)
constexpr int   B_    = 2048;
constexpr int   L_    = 8192;
constexpr int   G_    = 256;
constexpr float BETA_ = 0.01f;
constexpr float BIG_  = 1024.0f;   // y-flag encoding; |sum of log-terms| < 512 guaranteed

// log(sigmoid(-x)) = -softplus(x) = -(max(x,0) + log(1 + exp(-|x|)))
// HW transcendentals; validated absmax 0.0 vs threshold 5e-3 (R2-R4).
__device__ __forceinline__ float log_sigmoid_neg(float x) {
    return -(fmaxf(x, 0.0f) + __logf(1.0f + __expf(-fabsf(x))));
}

// ---------------------------------------------------------------------------
// k0: counting sort of labels by group -> per-label RANK (position in the
// group-sorted order) + group start offsets. Rank need not be stable --
// any within-group order works. One block; amortized over 2048 rows.
// ---------------------------------------------------------------------------
extern "C" __global__ __launch_bounds__(1024)
void build_rank_kernel(const int* __restrict__ group_ids,
                       int* __restrict__ g_offs,
                       int* __restrict__ g_rank)
{
    __shared__ int s_hist[G_];
    __shared__ int s_scan[G_];
    __shared__ int s_cur[G_];

    const int t = threadIdx.x;              // 0..1023

    if (t < G_) s_hist[t] = 0;

    // coalesced: element l = i*1024 + t
    int ids[8];
    #pragma unroll
    for (int i = 0; i < 8; ++i) ids[i] = group_ids[i * 1024 + t];

    __syncthreads();

    #pragma unroll
    for (int i = 0; i < 8; ++i) atomicAdd(&s_hist[ids[i]], 1);
    __syncthreads();

    // Hillis-Steele inclusive scan over 256 counts
    if (t < G_) s_scan[t] = s_hist[t];
    __syncthreads();
    for (int off = 1; off < G_; off <<= 1) {
        int v = 0;
        if (t < G_ && t >= off) v = s_scan[t - off];
        __syncthreads();
        if (t < G_) s_scan[t] += v;
        __syncthreads();
    }

    if (t < G_) {
        const int excl = s_scan[t] - s_hist[t];
        s_cur[t]  = excl;
        g_offs[t] = excl;
    }
    if (t == 0) g_offs[G_] = L_;
    __syncthreads();

    // rank assignment via per-group cursors; coalesced global write of rank
    #pragma unroll
    for (int i = 0; i < 8; ++i) {
        const int l = i * 1024 + t;
        g_rank[l] = atomicAdd(&s_cur[ids[i]], 1);
    }
}

// ---------------------------------------------------------------------------
// Main kernel: one block per row, zero hot-path atomics, zero indirection in
// the reduce phase.
// Phase 1: coalesced load logits/true_y/rank; softplus; encode y as +1024;
//          scatter s_row[rank[l]] = enc  (row lands in LDS already permuted).
// Phase 2: thread t owns group t: sum the CONTIGUOUS range s_row[o0..o1)
//          (independent ds_read_b32, fully pipelined -- R4's dependent
//          perm->row read chain is gone, and so is its 16KB LDS staging:
//          32.8KB -> 4 blocks/CU instead of 2).
// ---------------------------------------------------------------------------
extern "C" __global__ __launch_bounds__(256)
void meta_loss_kernel(const float* __restrict__ logits,
                      const int*   __restrict__ true_y,
                      const int*   __restrict__ g_offs,
                      const int*   __restrict__ g_rank,
                      float*       __restrict__ out)
{
    __shared__ float s_row[L_];              // 32 KB, permuted encoded row
    __shared__ float s_part[4];

    const int t = threadIdx.x;
    const int b = blockIdx.x;

    const float4* lg = (const float4*)(logits + (size_t)b * L_);
    const int4*   ty = (const int4*)(true_y + (size_t)b * L_);
    const int4*   rk = (const int4*)g_rank;

    // my group's extent (L2-hot)
    const int o0 = g_offs[t];
    const int o1 = g_offs[t + 1];

    // ---- Phase 1: stream row -> permuted encoded LDS ----
    #pragma unroll
    for (int i = 0; i < L_ / (4 * 256); ++i) {          // 8 iters
        const int idx = i * 256 + t;
        const float4 x = lg[idx];
        const int4   y = ty[idx];
        const int4   r = rk[idx];
        s_row[r.x] = log_sigmoid_neg(x.x) + (y.x ? BIG_ : 0.0f);
        s_row[r.y] = log_sigmoid_neg(x.y) + (y.y ? BIG_ : 0.0f);
        s_row[r.z] = log_sigmoid_neg(x.z) + (y.z ? BIG_ : 0.0f);
        s_row[r.w] = log_sigmoid_neg(x.w) + (y.w ? BIG_ : 0.0f);
    }
    __syncthreads();

    // ---- Phase 2: contiguous per-group sum + decode ----
    float enc = 0.0f;
    for (int j = o0; j < o1; ++j)
        enc += s_row[j];

    const int   k  = __float2int_rn(enc * (1.0f / BIG_));  // # true labels in group
    const float gl = enc - BIG_ * (float)k;                // sum log(1 - sigmoid)

    float term;
    if (k != 0) {
        term = fmaxf(gl, -100.0f);                    // meta_y = 1: log(p)
    } else {
        // gl == 0 (empty group) -> log1p(-1) = -inf -> clamped to -100
        term = fmaxf(log1pf(-__expf(gl)), -100.0f);   // meta_y = 0: log(1-p)
    }

    // block reduction
    #pragma unroll
    for (int off = 32; off > 0; off >>= 1)
        term += __shfl_down(term, off, 64);
    if ((t & 63) == 0) s_part[t >> 6] = term;
    __syncthreads();

    if (t == 0) {
        const float s = s_part[0] + s_part[1] + s_part[2] + s_part[3];
        atomicAdd(out, s * (-BETA_ / ((float)B_ * (float)G_)));
    }
}

extern "C" void kernel_launch(void* const* d_in, const int* in_sizes, int n_in,
                              void* d_out, int out_size, void* d_ws, size_t ws_size,
                              hipStream_t stream) {
    const float* logits    = (const float*)d_in[0];
    const int*   true_y    = (const int*)d_in[1];
    const int*   group_ids = (const int*)d_in[2];
    float*       out       = (float*)d_out;

    // workspace: [0, 2048) offs (257 ints used), [2048, 2048+32768) rank ints
    int* g_offs = (int*)d_ws;
    int* g_rank = (int*)((char*)d_ws + 2048);

    hipMemsetAsync(out, 0, sizeof(float), stream);

    build_rank_kernel<<<1, 1024, 0, stream>>>(group_ids, g_offs, g_rank);
    meta_loss_kernel<<<B_, 256, 0, stream>>>(logits, true_y, g_offs, g_rank, out);
}

// Round 6
// 152.479 us; speedup vs baseline: 1.3047x; 1.0616x over previous
//
#include <hip/hip_runtime.h>
#include <math.h>

// Problem constants (match reference)
constexpr int   B_    = 2048;
constexpr int   L_    = 8192;
constexpr int   G_    = 256;
constexpr float BETA_ = 0.01f;
constexpr float BIG_  = 1024.0f;   // y-flag encoding
constexpr int   PMAX  = L_ + G_ * 3;   // padded rank-space upper bound = 8960

// log(sigmoid(-x)) = -softplus(x) = -(max(x,0) + log(1 + exp(-|x|)))
// HW transcendentals; validated absmax 0.0 vs 5e-3 threshold (R2-R5).
__device__ __forceinline__ float log_sigmoid_neg(float x) {
    return -(fmaxf(x, 0.0f) + __logf(1.0f + __expf(-fabsf(x))));
}

// ---------------------------------------------------------------------------
// k0: counting sort -> PADDED rank space. Each group's extent is padded to a
// multiple of 4 floats (16B) so the main kernel's phase 2 can use aligned
// ds_read_b128. Pad slots are zero-filled by the main kernel and are additive
// identity. g_offs[g+1]-g_offs[g] = ceil(n_g/4)*4; total P <= 8960 (u16-safe).
// ---------------------------------------------------------------------------
extern "C" __global__ __launch_bounds__(1024)
void build_rank_kernel(const int* __restrict__ group_ids,
                       int* __restrict__ g_offs,
                       unsigned short* __restrict__ g_rank)
{
    __shared__ int s_hist[G_];
    __shared__ int s_scan[G_];
    __shared__ int s_cur[G_];

    const int t = threadIdx.x;              // 0..1023

    if (t < G_) s_hist[t] = 0;

    int ids[8];
    #pragma unroll
    for (int i = 0; i < 8; ++i) ids[i] = group_ids[i * 1024 + t];

    __syncthreads();

    #pragma unroll
    for (int i = 0; i < 8; ++i) atomicAdd(&s_hist[ids[i]], 1);
    __syncthreads();

    // inclusive scan over PADDED counts
    if (t < G_) s_scan[t] = (s_hist[t] + 3) & ~3;
    __syncthreads();
    for (int off = 1; off < G_; off <<= 1) {
        int v = 0;
        if (t < G_ && t >= off) v = s_scan[t - off];
        __syncthreads();
        if (t < G_) s_scan[t] += v;
        __syncthreads();
    }

    if (t < G_) {
        const int excl = s_scan[t] - ((s_hist[t] + 3) & ~3);  // padded start
        s_cur[t]  = excl;
        g_offs[t] = excl;
    }
    if (t == 0) g_offs[G_] = s_scan[G_ - 1];   // == padded start of group 256
    __syncthreads();

    // padded-space rank per label; coalesced u16 writes
    #pragma unroll
    for (int i = 0; i < 8; ++i) {
        const int l = i * 1024 + t;
        g_rank[l] = (unsigned short)atomicAdd(&s_cur[ids[i]], 1);
    }
}

// ---------------------------------------------------------------------------
// Main kernel: one block of 512 threads (8 waves) per row.
//  - LDS 35.9KB -> 4 blocks/CU -> 32 waves/CU (100% occupancy) to cover the
//    global-load latency that bounded R2-R5 (launch_bounds(512,8): VGPR<=64).
//  - Phase 2: aligned ds_read_b128 over the padded contiguous group extent,
//    float4 accumulator -> 4x fewer DS ops, independent loads (R5's serial
//    b32 latency chain is gone).
// ---------------------------------------------------------------------------
extern "C" __global__ __launch_bounds__(512, 8)
void meta_loss_kernel(const float* __restrict__ logits,
                      const int*   __restrict__ true_y,
                      const int*   __restrict__ g_offs,
                      const unsigned short* __restrict__ g_rank,
                      float*       __restrict__ out)
{
    __shared__ float s_row[PMAX];            // 35 KB, padded-permuted encoded row
    __shared__ float s_part[8];

    const int t = threadIdx.x;               // 0..511
    const int b = blockIdx.x;

    const float4*  lg = (const float4*)(logits + (size_t)b * L_);
    const int4*    ty = (const int4*)(true_y + (size_t)b * L_);
    const ushort4* rk = (const ushort4*)g_rank;
    float4* s_row4 = (float4*)s_row;

    // group extent (L2-hot); only first 256 threads own a group
    int o0 = 0, o1 = 0;
    if (t < G_) { o0 = g_offs[t]; o1 = g_offs[t + 1]; }

    // zero-init padded row (pad slots MUST be 0): 2240 float4
    #pragma unroll
    for (int i = 0; i < 5; ++i) {
        const int j = i * 512 + t;
        if (j < PMAX / 4) s_row4[j] = make_float4(0.f, 0.f, 0.f, 0.f);
    }
    __syncthreads();

    // ---- Phase 1: stream row -> padded-permuted encoded LDS ----
    #pragma unroll
    for (int i = 0; i < L_ / (4 * 512); ++i) {          // 4 iters
        const int idx = i * 512 + t;
        const float4  x = lg[idx];
        const int4    y = ty[idx];
        const ushort4 r = rk[idx];
        s_row[r.x] = log_sigmoid_neg(x.x) + (y.x ? BIG_ : 0.0f);
        s_row[r.y] = log_sigmoid_neg(x.y) + (y.y ? BIG_ : 0.0f);
        s_row[r.z] = log_sigmoid_neg(x.z) + (y.z ? BIG_ : 0.0f);
        s_row[r.w] = log_sigmoid_neg(x.w) + (y.w ? BIG_ : 0.0f);
    }
    __syncthreads();

    // ---- Phase 2: vectorized contiguous per-group sum + decode ----
    float term = 0.0f;
    if (t < G_) {
        float4 a4 = make_float4(0.f, 0.f, 0.f, 0.f);
        for (int j = o0; j < o1; j += 4) {
            const float4 v = *(const float4*)&s_row[j];
            a4.x += v.x; a4.y += v.y; a4.z += v.z; a4.w += v.w;
        }
        const float enc = (a4.x + a4.y) + (a4.z + a4.w);

        const int   k  = __float2int_rn(enc * (1.0f / BIG_));  // # true labels
        const float gl = enc - BIG_ * (float)k;                // sum log(1-sig)

        if (k != 0) {
            term = fmaxf(gl, -100.0f);                    // meta_y = 1: log(p)
        } else {
            // gl==0 (empty group) -> log1p(-1) = -inf -> clamped to -100
            term = fmaxf(log1pf(-__expf(gl)), -100.0f);   // meta_y = 0
        }
    }

    // block reduction (8 waves)
    #pragma unroll
    for (int off = 32; off > 0; off >>= 1)
        term += __shfl_down(term, off, 64);
    if ((t & 63) == 0) s_part[t >> 6] = term;
    __syncthreads();

    if (t == 0) {
        float s = 0.0f;
        #pragma unroll
        for (int w = 0; w < 8; ++w) s += s_part[w];
        atomicAdd(out, s * (-BETA_ / ((float)B_ * (float)G_)));
    }
}

extern "C" void kernel_launch(void* const* d_in, const int* in_sizes, int n_in,
                              void* d_out, int out_size, void* d_ws, size_t ws_size,
                              hipStream_t stream) {
    const float* logits    = (const float*)d_in[0];
    const int*   true_y    = (const int*)d_in[1];
    const int*   group_ids = (const int*)d_in[2];
    float*       out       = (float*)d_out;

    // workspace: [0, 2048) offs (257 ints used), [2048, 2048+16384) rank u16
    int*            g_offs = (int*)d_ws;
    unsigned short* g_rank = (unsigned short*)((char*)d_ws + 2048);

    hipMemsetAsync(out, 0, sizeof(float), stream);

    build_rank_kernel<<<1, 1024, 0, stream>>>(group_ids, g_offs, g_rank);
    meta_loss_kernel<<<B_, 512, 0, stream>>>(logits, true_y, g_offs, g_rank, out);
}